// Round 1
// 549.228 us; speedup vs baseline: 1.0594x; 1.0594x over previous
//
#include <hip/hip_runtime.h>
#include <hip/hip_bf16.h>
#include <stdint.h>
#include <type_traits>

// Problem constants (S=2048, B=4, H=1024, F=4096, E=8)
#define SB   8192
#define HDIM 1024
#define FDIM 4096
#define EDIM 8

typedef __bf16 bf16x8 __attribute__((ext_vector_type(8)));
typedef float  f32x4  __attribute__((ext_vector_type(4)));

__device__ __forceinline__ void g2l16(const void* g, void* l) {
  __builtin_amdgcn_global_load_lds(
      (const __attribute__((address_space(1))) uint32_t*)g,
      (__attribute__((address_space(3))) uint32_t*)l, 16, 0, 0);
}

__device__ __forceinline__ unsigned short f2bf(float f) {
  __hip_bfloat16 b = __float2bfloat16(f);
  return *reinterpret_cast<unsigned short*>(&b);
}

// ---------------- cast fp32 -> bf16 (vectorized) ----------------
__global__ void cast_bf16_kernel(const float4* __restrict__ in,
                                 ushort4* __restrict__ out, int n4) {
  int i = blockIdx.x * blockDim.x + threadIdx.x;
  if (i < n4) {
    float4 v = in[i];
    ushort4 o;
    o.x = f2bf(v.x); o.y = f2bf(v.y); o.z = f2bf(v.z); o.w = f2bf(v.w);
    out[i] = o;
  }
}

// ---------------- lambda: lam[e] = gb2[e] + dot(colsum, gw2[e,:]) / 8192 ----
__global__ void lam_kernel(const float* __restrict__ colsum,
                           const float* __restrict__ gw2,
                           const float* __restrict__ gb2,
                           float* __restrict__ lam) {
  __shared__ float red[256];
  const int tid = threadIdx.x;
  for (int e = 0; e < EDIM; ++e) {
    float p = 0.f;
    for (int h = tid; h < HDIM; h += 256) p += colsum[h] * gw2[e * HDIM + h];
    red[tid] = p;
    __syncthreads();
    for (int s = 128; s > 0; s >>= 1) {
      if (tid < s) red[tid] += red[tid + s];
      __syncthreads();
    }
    if (tid == 0) lam[e] = gb2[e] + red[0] * (1.f / 8192.f);
    __syncthreads();
  }
}

// ---------------- merge weights: out_bf16 = base + sum_e lam[e]*tv[e] ------
__global__ void merge_w_kernel(const float4* __restrict__ base,
                               const float4* __restrict__ tv,
                               const float* __restrict__ lam,
                               ushort4* __restrict__ outw, int n4) {
  int i = blockIdx.x * blockDim.x + threadIdx.x;
  if (i >= n4) return;
  float l[EDIM];
#pragma unroll
  for (int e = 0; e < EDIM; ++e) l[e] = lam[e];
  float4 v = base[i];
#pragma unroll
  for (int e = 0; e < EDIM; ++e) {
    float4 t = tv[(size_t)e * n4 + i];
    v.x += l[e] * t.x; v.y += l[e] * t.y; v.z += l[e] * t.z; v.w += l[e] * t.w;
  }
  ushort4 o;
  o.x = f2bf(v.x); o.y = f2bf(v.y); o.z = f2bf(v.z); o.w = f2bf(v.w);
  outw[i] = o;
}

// ---------------- merge biases (fp32 out, tiny) ----------------------------
__global__ void merge_b_kernel(const float* __restrict__ base,
                               const float* __restrict__ tv,
                               const float* __restrict__ lam,
                               float* __restrict__ outb, int n) {
  int i = blockIdx.x * blockDim.x + threadIdx.x;
  if (i >= n) return;
  float v = base[i];
#pragma unroll
  for (int e = 0; e < EDIM; ++e) v += lam[e] * tv[(size_t)e * n + i];
  outb[i] = v;
}

// ---------------------------------------------------------------------------
// 8-phase pipelined MFMA bt-GEMM: C[M,N] = A[M,K] * B[N,K]^T
// 256 x BN tile (BN in {256,128}), BK=64, 512 threads (8 waves = 2M x 4N),
// per-wave output 128 x (BN/4).  Double-buffered LDS, K-subtile-split
// regions: buffer = { A-k0[256x32], A-k1[256x32], B-k0[BNx32], B-k1[BNx32] }.
// LDS layout: 64B rows, XOR swizzle byte ^= ((byte>>7)&3)<<4 applied on the
// ds_read address AND (inverse == same, involution) on the global source
// address at staging; LDS dest of global_load_lds stays lane-linear (rule 21).
// Staging unit = 2 x global_load_lds_dwordx4 (8KB each, 512 thr x 16B).
// Counted waits: vmcnt(LEAD) only at phases 4 and 8 (LEAD=4 for BN=256,
// 2 for BN=128); vmcnt(0) only in the peeled last iteration.
// Schedule (race-traced): while computing tile t (phases 1-4, buf0) /
// t+1 (5-8, buf1):
//   p1: stage t+1 A-k1 -> buf1      p5: stage t+2 A-k1 -> buf0
//   p2: stage t+1 B(last) -> buf1   p6: stage t+2 B(last) -> buf0
//   p3: stage t+2 A-k0 -> buf0      p7: stage t+3 A-k0 -> buf1
//   p4: stage t+2 B-k0 -> buf0*     p8: stage t+3 B-k0 -> buf1*   (*BN=256)
// Each staged region was fully consumed >=1 phase earlier (lgkmcnt(0)
// before MFMA + trailing barrier => reads complete before overwrite issue).
// MODE 0: bias+relu, column-sum atomicAdd into Cout (float* colsum[N])
// MODE 1: bias+relu, store bf16
// MODE 2: bias, store fp32
template <int MODE, int BN>
__global__ void __launch_bounds__(512, 2)
gemm8p(const ushort* __restrict__ A, const ushort* __restrict__ B,
       const float* __restrict__ bias, void* __restrict__ Cout,
       int M, int N, int K) {
  constexpr int BM   = 256;
  constexpr int NF   = BN / 64;          // per-wave n-frags (4 or 2)
  constexpr int AREG = 256 * 32;         // elems per A k-region (16KB)
  constexpr int BREG = BN * 32;          // elems per B k-region
  constexpr int BUFSZ = 2 * AREG + 2 * BREG;
  constexpr int UPT  = (BN == 256) ? 4 : 3;  // stage units per K-tile
  constexpr int LEAD = (BN == 256) ? 4 : 2;  // steady-state vmcnt
  constexpr int U2   = (BN == 256) ? 3 : 2;  // "last B unit" id
  extern __shared__ __align__(16) ushort smem[];
  (void)M;

  const int tid  = threadIdx.x;
  const int lane = tid & 63;
  const int wave = tid >> 6;
  const int wm = wave >> 2, wn = wave & 3;
  const int lr = lane & 15, lq = lane >> 4;

  // XCD-aware swizzle (gridDim.y % 8 == 0)
  const int bid = blockIdx.y * gridDim.x + blockIdx.x;
  const int gx  = gridDim.x;
  const int Yc  = gridDim.y >> 3;
  const int xcd = bid & 7;
  const int tt  = bid >> 3;
  const int tq  = tt / gx;
  const int ty  = xcd * Yc + tq;
  const int tx  = tt - tq * gx;
  const int m0 = ty * BM, n0 = tx * BN;

  const int NT = K >> 6;  // K-tiles (BK=64); NT even, >= 4 for all our shapes

  f32x4 acc[8][NF];
#pragma unroll
  for (int i = 0; i < 8; ++i)
#pragma unroll
    for (int n = 0; n < NF; ++n)
#pragma unroll
      for (int r = 0; r < 4; ++r) acc[i][n][r] = 0.f;

  bf16x8 bfr[NF];

  // stage one unit (2 x 8KB chunks). u: 0=A-k0, 1=A-k1, 2=B-k0 (or B-all for
  // BN=128), 3=B-k1 (BN=256 only). Global col pre-swizzled (involution).
  auto stage_unit = [&](int buf, int u, int kt) {
    const int rr = tid >> 2;
    const int ps = tid & 3;
    if (u < 2) {
      ushort* l = smem + buf * BUFSZ + u * AREG + tid * 8;
#pragma unroll
      for (int c = 0; c < 2; ++c) {
        const int row = c * 128 + rr;
        const int col = (ps ^ ((row >> 1) & 3)) * 8;
        g2l16(A + (size_t)(m0 + row) * K + kt * 64 + u * 32 + col, l + c * 4096);
      }
    } else if (BN == 256) {
      const int ks = u - 2;
      ushort* l = smem + buf * BUFSZ + 2 * AREG + ks * BREG + tid * 8;
#pragma unroll
      for (int c = 0; c < 2; ++c) {
        const int row = c * 128 + rr;
        const int col = (ps ^ ((row >> 1) & 3)) * 8;
        g2l16(B + (size_t)(n0 + row) * K + kt * 64 + ks * 32 + col, l + c * 4096);
      }
    } else {  // BN==128: both B regions (chunk c == k-subtile c)
      ushort* l = smem + buf * BUFSZ + 2 * AREG + tid * 8;
      const int row = rr;
      const int col = (ps ^ ((row >> 1) & 3)) * 8;
#pragma unroll
      for (int c = 0; c < 2; ++c) {
        g2l16(B + (size_t)(n0 + row) * K + kt * 64 + c * 32 + col, l + c * 4096);
      }
    }
  };

  auto ldA = [&](int buf, int ks, int mi) -> bf16x8 {
    const int row = wm * 128 + mi * 16 + lr;
    const int off = buf * BUFSZ + ks * AREG + row * 32 +
                    ((lq ^ ((row >> 1) & 3)) * 8);
    return *reinterpret_cast<const bf16x8*>(&smem[off]);
  };
  auto ldB = [&](int buf, int ks, int ni) -> bf16x8 {
    const int row = wn * (BN / 4) + ni * 16 + lr;
    const int off = buf * BUFSZ + 2 * AREG + ks * BREG + row * 32 +
                    ((lq ^ ((row >> 1) & 3)) * 8);
    return *reinterpret_cast<const bf16x8*>(&smem[off]);
  };

  // one phase: {ds_read subtile, stage 1 unit} -> barrier -> lgkmcnt(0) ->
  // setprio(1) MFMA x 4*NF setprio(0) -> [vmcnt(tail)] barrier
  auto do_phase = [&](int buf, int ks, auto mhc, auto&& stage_fn, int tail) {
    constexpr int MH = decltype(mhc)::value;
    bf16x8 afr[4];
#pragma unroll
    for (int i = 0; i < 4; ++i) afr[i] = ldA(buf, ks, MH * 4 + i);
    if constexpr (MH == 0) {
#pragma unroll
      for (int n = 0; n < NF; ++n) bfr[n] = ldB(buf, ks, n);
    }
    stage_fn();
    __builtin_amdgcn_sched_barrier(0);
    asm volatile("s_barrier\n\ts_waitcnt lgkmcnt(0)" ::: "memory");
    __builtin_amdgcn_sched_barrier(0);
    __builtin_amdgcn_s_setprio(1);
#pragma unroll
    for (int i = 0; i < 4; ++i)
#pragma unroll
      for (int n = 0; n < NF; ++n)
        acc[MH * 4 + i][n] = __builtin_amdgcn_mfma_f32_16x16x32_bf16(
            afr[i], bfr[n], acc[MH * 4 + i][n], 0, 0, 0);
    __builtin_amdgcn_s_setprio(0);
    __builtin_amdgcn_sched_barrier(0);
    if (tail < 0)       asm volatile("s_barrier" ::: "memory");
    else if (tail == 4) asm volatile("s_waitcnt vmcnt(4)\n\ts_barrier" ::: "memory");
    else if (tail == 2) asm volatile("s_waitcnt vmcnt(2)\n\ts_barrier" ::: "memory");
    else                asm volatile("s_waitcnt vmcnt(0)\n\ts_barrier" ::: "memory");
    __builtin_amdgcn_sched_barrier(0);
  };

  // ---- prologue: tile0 fully, tile1 first units; leave LEAD loads in flight
#pragma unroll
  for (int u = 0; u < UPT; ++u) stage_unit(0, u, 0);
  stage_unit(1, 0, 1);
  if (BN == 256) stage_unit(1, 2, 1);
  __builtin_amdgcn_sched_barrier(0);
  if constexpr (BN == 256)
    asm volatile("s_waitcnt vmcnt(4)\n\ts_barrier" ::: "memory");
  else
    asm volatile("s_waitcnt vmcnt(2)\n\ts_barrier" ::: "memory");
  __builtin_amdgcn_sched_barrier(0);

  using I0 = std::integral_constant<int, 0>;
  using I1 = std::integral_constant<int, 1>;

  auto iter2 = [&](int t, auto lastc) {
    constexpr bool LAST = decltype(lastc)::value;
    do_phase(0, 0, I0{}, [&] { stage_unit(1, 1, t + 1); }, -1);
    do_phase(0, 0, I1{}, [&] { stage_unit(1, U2, t + 1); }, -1);
    do_phase(0, 1, I0{}, [&] { if (!LAST) stage_unit(0, 0, t + 2); }, -1);
    do_phase(0, 1, I1{},
             [&] { if (!LAST && BN == 256) stage_unit(0, 2, t + 2); },
             LAST ? 0 : LEAD);
    do_phase(1, 0, I0{}, [&] { if (!LAST) stage_unit(0, 1, t + 2); }, -1);
    do_phase(1, 0, I1{}, [&] { if (!LAST) stage_unit(0, U2, t + 2); }, -1);
    do_phase(1, 1, I0{}, [&] { if (!LAST) stage_unit(1, 0, t + 3); }, -1);
    do_phase(1, 1, I1{},
             [&] { if (!LAST && BN == 256) stage_unit(1, 2, t + 3); },
             LAST ? -1 : LEAD);
  };

  int t = 0;
  for (; t < NT - 2; t += 2) iter2(t, std::false_type{});
  iter2(t, std::true_type{});

  // ---- epilogue.  C/D layout (verified m89/m91): col=ni*16+lr, row=lq*4+r.
  const int gm = m0 + wm * 128;
  const int gn = n0 + wn * (BN / 4);
  if constexpr (MODE == 0) {
    float* colsum = (float*)Cout;
#pragma unroll
    for (int ni = 0; ni < NF; ++ni) {
      const int col = gn + ni * 16 + lr;
      const float bv = bias[col];
      float p = 0.f;
#pragma unroll
      for (int mi = 0; mi < 8; ++mi)
#pragma unroll
        for (int r = 0; r < 4; ++r) {
          float v = acc[mi][ni][r] + bv;
          p += v > 0.f ? v : 0.f;
        }
      p += __shfl_xor(p, 16);
      p += __shfl_xor(p, 32);
      if (lq == 0) atomicAdd(&colsum[col], p);
    }
  } else if constexpr (MODE == 1) {
    __hip_bfloat16* C = (__hip_bfloat16*)Cout;
#pragma unroll
    for (int ni = 0; ni < NF; ++ni) {
      const int col = gn + ni * 16 + lr;
      const float bv = bias[col];
#pragma unroll
      for (int mi = 0; mi < 8; ++mi)
#pragma unroll
        for (int r = 0; r < 4; ++r) {
          const int row = gm + mi * 16 + lq * 4 + r;
          float v = acc[mi][ni][r] + bv;
          v = v > 0.f ? v : 0.f;
          C[(size_t)row * N + col] = __float2bfloat16(v);
        }
    }
  } else {
    float* C = (float*)Cout;
#pragma unroll
    for (int ni = 0; ni < NF; ++ni) {
      const int col = gn + ni * 16 + lr;
      const float bv = bias[col];
#pragma unroll
      for (int mi = 0; mi < 8; ++mi)
#pragma unroll
        for (int r = 0; r < 4; ++r) {
          const int row = gm + mi * 16 + lq * 4 + r;
          C[(size_t)row * N + col] = acc[mi][ni][r] + bv;
        }
    }
  }
}

// ---------------------------------------------------------------------------
extern "C" void kernel_launch(void* const* d_in, const int* in_sizes, int n_in,
                              void* d_out, int out_size, void* d_ws, size_t ws_size,
                              hipStream_t stream) {
  const float* X   = (const float*)d_in[0];   // [S,B,H]
  const float* gw1 = (const float*)d_in[1];   // [H,H]
  const float* gb1 = (const float*)d_in[2];   // [H]
  const float* gw2 = (const float*)d_in[3];   // [E,H]
  const float* gb2 = (const float*)d_in[4];   // [E]
  const float* bw1 = (const float*)d_in[5];   // [F,H]
  const float* bb1 = (const float*)d_in[6];   // [F]
  const float* bw2 = (const float*)d_in[7];   // [H,F]
  const float* bb2 = (const float*)d_in[8];   // [H]
  const float* tw1 = (const float*)d_in[9];   // [E,F,H]
  const float* tb1 = (const float*)d_in[10];  // [E,F]
  const float* tw2 = (const float*)d_in[11];  // [E,H,F]
  const float* tb2 = (const float*)d_in[12];  // [E,H]
  float* out = (float*)d_out;                 // [S,B,H]

  // one-time: allow >64KB dynamic LDS for the pipelined GEMMs
  static bool s_attr = false;
  if (!s_attr) {
    (void)hipFuncSetAttribute(reinterpret_cast<const void*>(gemm8p<0, 128>),
                              hipFuncAttributeMaxDynamicSharedMemorySize, 98304);
    (void)hipFuncSetAttribute(reinterpret_cast<const void*>(gemm8p<2, 128>),
                              hipFuncAttributeMaxDynamicSharedMemorySize, 98304);
    (void)hipFuncSetAttribute(reinterpret_cast<const void*>(gemm8p<1, 256>),
                              hipFuncAttributeMaxDynamicSharedMemorySize, 131072);
    s_attr = true;
  }

  // workspace carve (256B aligned)
  size_t off = 0;
  auto carve = [&](size_t bytes) -> void* {
    void* p = (char*)d_ws + off;
    off += (bytes + 255) & ~(size_t)255;
    return p;
  };
  ushort* Xbf   = (ushort*)carve((size_t)SB * HDIM * 2);     // X in bf16
  ushort* gw1bf = (ushort*)carve((size_t)HDIM * HDIM * 2);   // gate w1 bf16
  ushort* w1m   = (ushort*)carve((size_t)FDIM * HDIM * 2);   // merged w1 bf16
  ushort* w2m   = (ushort*)carve((size_t)HDIM * FDIM * 2);   // merged w2 bf16
  ushort* hbuf  = (ushort*)carve((size_t)SB * FDIM * 2);     // h bf16
  float* b1m    = (float*)carve(FDIM * 4);
  float* b2m    = (float*)carve(HDIM * 4);
  float* colsum = (float*)carve(HDIM * 4);
  float* lam    = (float*)carve(EDIM * 4);

  // 1) casts to bf16
  {
    int n4 = SB * HDIM / 4;
    cast_bf16_kernel<<<(n4 + 255) / 256, 256, 0, stream>>>(
        (const float4*)X, (ushort4*)Xbf, n4);
    n4 = HDIM * HDIM / 4;
    cast_bf16_kernel<<<(n4 + 255) / 256, 256, 0, stream>>>(
        (const float4*)gw1, (ushort4*)gw1bf, n4);
  }

  // 2) zero colsum accumulator (ws is poisoned before each call)
  hipMemsetAsync(colsum, 0, HDIM * sizeof(float), stream);

  // 3) gate GEMM -> relu -> column sums  (M=8192, N=1024, K=1024)
  gemm8p<0, 128><<<dim3(HDIM / 128, SB / 256), 512, 98304, stream>>>(
      Xbf, gw1bf, gb1, colsum, SB, HDIM, HDIM);

  // 4) lambda
  lam_kernel<<<1, 256, 0, stream>>>(colsum, gw2, gb2, lam);

  // 5) merge weights + biases
  {
    int n4 = FDIM * HDIM / 4;
    merge_w_kernel<<<(n4 + 255) / 256, 256, 0, stream>>>(
        (const float4*)bw1, (const float4*)tw1, lam, (ushort4*)w1m, n4);
    merge_w_kernel<<<(n4 + 255) / 256, 256, 0, stream>>>(
        (const float4*)bw2, (const float4*)tw2, lam, (ushort4*)w2m, n4);
    merge_b_kernel<<<(FDIM + 255) / 256, 256, 0, stream>>>(bb1, tb1, lam, b1m, FDIM);
    merge_b_kernel<<<(HDIM + 255) / 256, 256, 0, stream>>>(bb2, tb2, lam, b2m, HDIM);
  }

  // 6) h = relu(X @ w1m^T + b1m)   (M=8192, N=4096, K=1024), bf16 out
  gemm8p<1, 256><<<dim3(FDIM / 256, SB / 256), 512, 131072, stream>>>(
      Xbf, w1m, b1m, hbuf, SB, FDIM, HDIM);

  // 7) out = h @ w2m^T + b2m       (M=8192, N=1024, K=4096), fp32 out
  gemm8p<2, 128><<<dim3(HDIM / 128, SB / 256), 512, 98304, stream>>>(
      hbuf, w2m, b2m, out, SB, HDIM, FDIM);
}

// Round 2
// 541.671 us; speedup vs baseline: 1.0742x; 1.0140x over previous
//
#include <hip/hip_runtime.h>
#include <hip/hip_bf16.h>
#include <stdint.h>
#include <type_traits>

// Problem constants (S=2048, B=4, H=1024, F=4096, E=8)
#define SB   8192
#define HDIM 1024
#define FDIM 4096
#define EDIM 8

typedef __bf16 bf16x8 __attribute__((ext_vector_type(8)));
typedef float  f32x4  __attribute__((ext_vector_type(4)));

__device__ __forceinline__ void g2l16(const void* g, void* l) {
  __builtin_amdgcn_global_load_lds(
      (const __attribute__((address_space(1))) uint32_t*)g,
      (__attribute__((address_space(3))) uint32_t*)l, 16, 0, 0);
}

__device__ __forceinline__ unsigned short f2bf(float f) {
  __hip_bfloat16 b = __float2bfloat16(f);
  return *reinterpret_cast<unsigned short*>(&b);
}

// inline-asm ds_read_b128 with compile-time offset immediate.  Keeps the
// compiler's waitcnt pass out of the loop (no C++ LDS load that aliases the
// global_load_lds destination -> no auto vmcnt(0) drains); we do our own
// lgkmcnt(0) + sched_barrier(0) (rule #18).
template <int IMM>
__device__ __forceinline__ bf16x8 lds_rd128(int addr) {
  bf16x8 r;
  asm volatile("ds_read_b128 %0, %1 offset:%2" : "=v"(r) : "v"(addr), "n"(IMM));
  return r;
}

// ---------------- cast fp32 -> bf16 (vectorized) ----------------
__global__ void cast_bf16_kernel(const float4* __restrict__ in,
                                 ushort4* __restrict__ out, int n4) {
  int i = blockIdx.x * blockDim.x + threadIdx.x;
  if (i < n4) {
    float4 v = in[i];
    ushort4 o;
    o.x = f2bf(v.x); o.y = f2bf(v.y); o.z = f2bf(v.z); o.w = f2bf(v.w);
    out[i] = o;
  }
}

// ---------------- lambda: lam[e] = gb2[e] + dot(colsum, gw2[e,:]) / 8192 ----
__global__ void lam_kernel(const float* __restrict__ colsum,
                           const float* __restrict__ gw2,
                           const float* __restrict__ gb2,
                           float* __restrict__ lam) {
  __shared__ float red[256];
  const int tid = threadIdx.x;
  for (int e = 0; e < EDIM; ++e) {
    float p = 0.f;
    for (int h = tid; h < HDIM; h += 256) p += colsum[h] * gw2[e * HDIM + h];
    red[tid] = p;
    __syncthreads();
    for (int s = 128; s > 0; s >>= 1) {
      if (tid < s) red[tid] += red[tid + s];
      __syncthreads();
    }
    if (tid == 0) lam[e] = gb2[e] + red[0] * (1.f / 8192.f);
    __syncthreads();
  }
}

// ---------------- merge weights: out_bf16 = base + sum_e lam[e]*tv[e] ------
__global__ void merge_w_kernel(const float4* __restrict__ base,
                               const float4* __restrict__ tv,
                               const float* __restrict__ lam,
                               ushort4* __restrict__ outw, int n4) {
  int i = blockIdx.x * blockDim.x + threadIdx.x;
  if (i >= n4) return;
  float l[EDIM];
#pragma unroll
  for (int e = 0; e < EDIM; ++e) l[e] = lam[e];
  float4 v = base[i];
#pragma unroll
  for (int e = 0; e < EDIM; ++e) {
    float4 t = tv[(size_t)e * n4 + i];
    v.x += l[e] * t.x; v.y += l[e] * t.y; v.z += l[e] * t.z; v.w += l[e] * t.w;
  }
  ushort4 o;
  o.x = f2bf(v.x); o.y = f2bf(v.y); o.z = f2bf(v.z); o.w = f2bf(v.w);
  outw[i] = o;
}

// ---------------- merge biases (fp32 out, tiny) ----------------------------
__global__ void merge_b_kernel(const float* __restrict__ base,
                               const float* __restrict__ tv,
                               const float* __restrict__ lam,
                               float* __restrict__ outb, int n) {
  int i = blockIdx.x * blockDim.x + threadIdx.x;
  if (i >= n) return;
  float v = base[i];
#pragma unroll
  for (int e = 0; e < EDIM; ++e) v += lam[e] * tv[(size_t)e * n + i];
  outb[i] = v;
}

// ---------------------------------------------------------------------------
// 8-phase pipelined MFMA bt-GEMM: C[M,N] = A[M,K] * B[N,K]^T
// Same schedule as R1 (race-traced, verified):
//   p1: stage t+1 A-k1 -> buf1      p5: stage t+2 A-k1 -> buf0
//   p2: stage t+1 B(last) -> buf1   p6: stage t+2 B(last) -> buf0
//   p3: stage t+2 A-k0 -> buf0      p7: stage t+3 A-k0 -> buf1
//   p4: stage t+2 B-k0 -> buf0*     p8: stage t+3 B-k0 -> buf1*   (*BN=256)
// vmcnt(LEAD) at p4/p8 only (LEAD=4 BN=256, 2 BN=128); vmcnt(0) only in the
// peeled last iteration.
// R2 change: ALL in-loop LDS reads are inline-asm ds_read_b128 with immediate
// offsets off 4 per-lane base regs (vA0/vA1/vB0/vB1); barriers are raw
// __builtin_amdgcn_s_barrier(); waitcnts are bare asm (NO memory clobber) so
// the compiler's waitcnt pass cannot inject vmcnt(0) drains into the pipeline.
// Ordering pinned by sched_barrier(0) at every seam.
template <int MODE, int BN>
__global__ void __launch_bounds__(512, 2)
gemm8p(const ushort* __restrict__ A, const ushort* __restrict__ B,
       const float* __restrict__ bias, void* __restrict__ Cout,
       int M, int N, int K) {
  constexpr int BM   = 256;
  constexpr int NF   = BN / 64;          // per-wave n-frags (4 or 2)
  constexpr int AREG = 256 * 32;         // elems per A k-region (16KB)
  constexpr int BREG = BN * 32;          // elems per B k-region
  constexpr int BUFSZ = 2 * AREG + 2 * BREG;  // elems per buffer
  constexpr int BUFB  = BUFSZ * 2;            // bytes per buffer
  constexpr int UPT  = (BN == 256) ? 4 : 3;   // stage units per K-tile
  constexpr int U2   = (BN == 256) ? 3 : 2;   // "last B unit" id
  extern __shared__ __align__(16) ushort smem[];
  (void)M;

  const int tid  = threadIdx.x;
  const int lane = tid & 63;
  const int wave = tid >> 6;
  const int wm = wave >> 2, wn = wave & 3;
  const int lr = lane & 15, lq = lane >> 4;

  // XCD-aware swizzle (gridDim.y % 8 == 0)
  const int bid = blockIdx.y * gridDim.x + blockIdx.x;
  const int gx  = gridDim.x;
  const int Yc  = gridDim.y >> 3;
  const int xcd = bid & 7;
  const int tt  = bid >> 3;
  const int tq  = tt / gx;
  const int ty  = xcd * Yc + tq;
  const int tx  = tt - tq * gx;
  const int m0 = ty * BM, n0 = tx * BN;

  const int NT = K >> 6;  // K-tiles (BK=64); even, >= 4 for all our shapes

  // ---- per-lane LDS read base addresses (swizzle term is lane-constant:
  // row = base + mi*16 (+16 steps keep (row>>1)&3 invariant))
  const uint32_t smemBase =
      (uint32_t)(uintptr_t)(__attribute__((address_space(3))) ushort*)smem;
  const int rowAl = wm * 128 + lr;
  const int vA0 = (int)smemBase + rowAl * 64 + ((lq ^ ((rowAl >> 1) & 3)) << 4);
  const int vA1 = vA0 + BUFB;
  const int rowBl = wn * (BN / 4) + lr;
  const int vB0 = (int)smemBase + 2 * AREG * 2 + rowBl * 64 +
                  ((lq ^ ((rowBl >> 1) & 3)) << 4);
  const int vB1 = vB0 + BUFB;

  // ---- per-thread staging pointers (global src pre-swizzled, LDS dest
  // lane-linear; rule #21).  Swizzle col is identical for row and row+128.
  const int rr = tid >> 2;
  const int colS = ((tid & 3) ^ ((rr >> 1) & 3)) * 8;
  const ushort* gA0p = A + (size_t)(m0 + rr) * K + colS;
  const ushort* gA1p = gA0p + (size_t)128 * K;
  const ushort* gB0p = B + (size_t)(n0 + rr) * K + colS;
  const ushort* gB1p = gB0p + (size_t)128 * K;  // used only when BN==256
  ushort* lds0 = smem + tid * 8;

  f32x4 acc[8][NF];
#pragma unroll
  for (int i = 0; i < 8; ++i)
#pragma unroll
    for (int n = 0; n < NF; ++n)
#pragma unroll
      for (int r = 0; r < 4; ++r) acc[i][n][r] = 0.f;

  bf16x8 bfr[NF];

  // stage one unit (2 x global_load_lds_dwordx4 per thread = 16KB)
  auto stage_unit = [&](int buf, int u, int kt) {
    const int bo = buf * BUFSZ;
    const int kk = kt * 64;
    if (u < 2) {
      ushort* l = lds0 + bo + u * AREG;
      g2l16(gA0p + kk + u * 32, l);
      g2l16(gA1p + kk + u * 32, l + 4096);
    } else if (BN == 256) {
      const int ks = u - 2;
      ushort* l = lds0 + bo + 2 * AREG + ks * BREG;
      g2l16(gB0p + kk + ks * 32, l);
      g2l16(gB1p + kk + ks * 32, l + 4096);
    } else {  // BN==128: both k-subtiles of B in one unit
      ushort* l = lds0 + bo + 2 * AREG;
      g2l16(gB0p + kk, l);
      g2l16(gB0p + kk + 32, l + 4096);
    }
  };

  // one phase
  auto do_phase = [&](auto bufc, auto ksc, auto mhc, auto&& stage_fn, int tail) {
    constexpr int BUF = decltype(bufc)::value;
    constexpr int KS  = decltype(ksc)::value;
    constexpr int MH  = decltype(mhc)::value;
    const int vAb = BUF ? vA1 : vA0;
    bf16x8 afr[4];
    afr[0] = lds_rd128<KS * 16384 + (MH * 4 + 0) * 1024>(vAb);
    afr[1] = lds_rd128<KS * 16384 + (MH * 4 + 1) * 1024>(vAb);
    afr[2] = lds_rd128<KS * 16384 + (MH * 4 + 2) * 1024>(vAb);
    afr[3] = lds_rd128<KS * 16384 + (MH * 4 + 3) * 1024>(vAb);
    if constexpr (MH == 0) {
      const int vBb = BUF ? vB1 : vB0;
      bfr[0] = lds_rd128<KS * (BN * 64) + 0 * 1024>(vBb);
      bfr[1] = lds_rd128<KS * (BN * 64) + 1 * 1024>(vBb);
      if constexpr (NF == 4) {
        bfr[2] = lds_rd128<KS * (BN * 64) + 2 * 1024>(vBb);
        bfr[3] = lds_rd128<KS * (BN * 64) + 3 * 1024>(vBb);
      }
    }
    stage_fn();
    __builtin_amdgcn_sched_barrier(0);
    __builtin_amdgcn_s_barrier();
    asm volatile("s_waitcnt lgkmcnt(0)");
    __builtin_amdgcn_sched_barrier(0);
    __builtin_amdgcn_s_setprio(1);
#pragma unroll
    for (int i = 0; i < 4; ++i)
#pragma unroll
      for (int n = 0; n < NF; ++n)
        acc[MH * 4 + i][n] = __builtin_amdgcn_mfma_f32_16x16x32_bf16(
            afr[i], bfr[n], acc[MH * 4 + i][n], 0, 0, 0);
    __builtin_amdgcn_s_setprio(0);
    __builtin_amdgcn_sched_barrier(0);
    if (tail == -1) {
      __builtin_amdgcn_s_barrier();
    } else if (tail == 4) {
      asm volatile("s_waitcnt vmcnt(4)");
      __builtin_amdgcn_s_barrier();
    } else if (tail == 2) {
      asm volatile("s_waitcnt vmcnt(2)");
      __builtin_amdgcn_s_barrier();
    } else {
      asm volatile("s_waitcnt vmcnt(0)");
      __builtin_amdgcn_s_barrier();
    }
    __builtin_amdgcn_sched_barrier(0);
  };

  // ---- prologue: tile0 fully, tile1 first units; leave steady-state loads
  // in flight (matches p1-entry state: A-k0 + B-k0 of next tile in flight)
#pragma unroll
  for (int u = 0; u < UPT; ++u) stage_unit(0, u, 0);
  stage_unit(1, 0, 1);
  if (BN == 256) stage_unit(1, 2, 1);
  __builtin_amdgcn_sched_barrier(0);
  if constexpr (BN == 256)
    asm volatile("s_waitcnt vmcnt(4)");
  else
    asm volatile("s_waitcnt vmcnt(2)");
  __builtin_amdgcn_s_barrier();
  __builtin_amdgcn_sched_barrier(0);

  using I0 = std::integral_constant<int, 0>;
  using I1 = std::integral_constant<int, 1>;
  constexpr int LEAD = (BN == 256) ? 4 : 2;

  auto iter2 = [&](int t, auto lastc) {
    constexpr bool LAST = decltype(lastc)::value;
    do_phase(I0{}, I0{}, I0{}, [&] { stage_unit(1, 1, t + 1); }, -1);
    do_phase(I0{}, I0{}, I1{}, [&] { stage_unit(1, U2, t + 1); }, -1);
    do_phase(I0{}, I1{}, I0{}, [&] { if (!LAST) stage_unit(0, 0, t + 2); }, -1);
    do_phase(I0{}, I1{}, I1{},
             [&] { if (!LAST && BN == 256) stage_unit(0, 2, t + 2); },
             LAST ? 0 : LEAD);
    do_phase(I1{}, I0{}, I0{}, [&] { if (!LAST) stage_unit(0, 1, t + 2); }, -1);
    do_phase(I1{}, I0{}, I1{}, [&] { if (!LAST) stage_unit(0, U2, t + 2); }, -1);
    do_phase(I1{}, I1{}, I0{}, [&] { if (!LAST) stage_unit(1, 0, t + 3); }, -1);
    do_phase(I1{}, I1{}, I1{},
             [&] { if (!LAST && BN == 256) stage_unit(1, 2, t + 3); },
             LAST ? -1 : LEAD);
  };

  int t = 0;
  for (; t < NT - 2; t += 2) iter2(t, std::false_type{});
  iter2(t, std::true_type{});

  // ---- epilogue.  C/D layout (verified m89/m91): col=ni*16+lr, row=lq*4+r.
  const int gm = m0 + wm * 128;
  const int gn = n0 + wn * (BN / 4);
  if constexpr (MODE == 0) {
    float* colsum = (float*)Cout;
#pragma unroll
    for (int ni = 0; ni < NF; ++ni) {
      const int col = gn + ni * 16 + lr;
      const float bv = bias[col];
      float p = 0.f;
#pragma unroll
      for (int mi = 0; mi < 8; ++mi)
#pragma unroll
        for (int r = 0; r < 4; ++r) {
          float v = acc[mi][ni][r] + bv;
          p += v > 0.f ? v : 0.f;
        }
      p += __shfl_xor(p, 16);
      p += __shfl_xor(p, 32);
      if (lq == 0) atomicAdd(&colsum[col], p);
    }
  } else if constexpr (MODE == 1) {
    __hip_bfloat16* C = (__hip_bfloat16*)Cout;
#pragma unroll
    for (int ni = 0; ni < NF; ++ni) {
      const int col = gn + ni * 16 + lr;
      const float bv = bias[col];
#pragma unroll
      for (int mi = 0; mi < 8; ++mi)
#pragma unroll
        for (int r = 0; r < 4; ++r) {
          const int row = gm + mi * 16 + lq * 4 + r;
          float v = acc[mi][ni][r] + bv;
          v = v > 0.f ? v : 0.f;
          C[(size_t)row * N + col] = __float2bfloat16(v);
        }
    }
  } else {
    float* C = (float*)Cout;
#pragma unroll
    for (int ni = 0; ni < NF; ++ni) {
      const int col = gn + ni * 16 + lr;
      const float bv = bias[col];
#pragma unroll
      for (int mi = 0; mi < 8; ++mi)
#pragma unroll
        for (int r = 0; r < 4; ++r) {
          const int row = gm + mi * 16 + lq * 4 + r;
          C[(size_t)row * N + col] = acc[mi][ni][r] + bv;
        }
    }
  }
}

// ---------------------------------------------------------------------------
extern "C" void kernel_launch(void* const* d_in, const int* in_sizes, int n_in,
                              void* d_out, int out_size, void* d_ws, size_t ws_size,
                              hipStream_t stream) {
  const float* X   = (const float*)d_in[0];   // [S,B,H]
  const float* gw1 = (const float*)d_in[1];   // [H,H]
  const float* gb1 = (const float*)d_in[2];   // [H]
  const float* gw2 = (const float*)d_in[3];   // [E,H]
  const float* gb2 = (const float*)d_in[4];   // [E]
  const float* bw1 = (const float*)d_in[5];   // [F,H]
  const float* bb1 = (const float*)d_in[6];   // [F]
  const float* bw2 = (const float*)d_in[7];   // [H,F]
  const float* bb2 = (const float*)d_in[8];   // [H]
  const float* tw1 = (const float*)d_in[9];   // [E,F,H]
  const float* tb1 = (const float*)d_in[10];  // [E,F]
  const float* tw2 = (const float*)d_in[11];  // [E,H,F]
  const float* tb2 = (const float*)d_in[12];  // [E,H]
  float* out = (float*)d_out;                 // [S,B,H]

  // one-time: allow >64KB dynamic LDS for the pipelined GEMMs
  static bool s_attr = false;
  if (!s_attr) {
    (void)hipFuncSetAttribute(reinterpret_cast<const void*>(gemm8p<0, 128>),
                              hipFuncAttributeMaxDynamicSharedMemorySize, 98304);
    (void)hipFuncSetAttribute(reinterpret_cast<const void*>(gemm8p<2, 128>),
                              hipFuncAttributeMaxDynamicSharedMemorySize, 98304);
    (void)hipFuncSetAttribute(reinterpret_cast<const void*>(gemm8p<1, 256>),
                              hipFuncAttributeMaxDynamicSharedMemorySize, 131072);
    s_attr = true;
  }

  // workspace carve (256B aligned)
  size_t off = 0;
  auto carve = [&](size_t bytes) -> void* {
    void* p = (char*)d_ws + off;
    off += (bytes + 255) & ~(size_t)255;
    return p;
  };
  ushort* Xbf   = (ushort*)carve((size_t)SB * HDIM * 2);     // X in bf16
  ushort* gw1bf = (ushort*)carve((size_t)HDIM * HDIM * 2);   // gate w1 bf16
  ushort* w1m   = (ushort*)carve((size_t)FDIM * HDIM * 2);   // merged w1 bf16
  ushort* w2m   = (ushort*)carve((size_t)HDIM * FDIM * 2);   // merged w2 bf16
  ushort* hbuf  = (ushort*)carve((size_t)SB * FDIM * 2);     // h bf16
  float* b1m    = (float*)carve(FDIM * 4);
  float* b2m    = (float*)carve(HDIM * 4);
  float* colsum = (float*)carve(HDIM * 4);
  float* lam    = (float*)carve(EDIM * 4);

  // 1) casts to bf16
  {
    int n4 = SB * HDIM / 4;
    cast_bf16_kernel<<<(n4 + 255) / 256, 256, 0, stream>>>(
        (const float4*)X, (ushort4*)Xbf, n4);
    n4 = HDIM * HDIM / 4;
    cast_bf16_kernel<<<(n4 + 255) / 256, 256, 0, stream>>>(
        (const float4*)gw1, (ushort4*)gw1bf, n4);
  }

  // 2) zero colsum accumulator (ws is poisoned before each call)
  hipMemsetAsync(colsum, 0, HDIM * sizeof(float), stream);

  // 3) gate GEMM -> relu -> column sums  (M=8192, N=1024, K=1024)
  gemm8p<0, 128><<<dim3(HDIM / 128, SB / 256), 512, 98304, stream>>>(
      Xbf, gw1bf, gb1, colsum, SB, HDIM, HDIM);

  // 4) lambda
  lam_kernel<<<1, 256, 0, stream>>>(colsum, gw2, gb2, lam);

  // 5) merge weights + biases
  {
    int n4 = FDIM * HDIM / 4;
    merge_w_kernel<<<(n4 + 255) / 256, 256, 0, stream>>>(
        (const float4*)bw1, (const float4*)tw1, lam, (ushort4*)w1m, n4);
    merge_w_kernel<<<(n4 + 255) / 256, 256, 0, stream>>>(
        (const float4*)bw2, (const float4*)tw2, lam, (ushort4*)w2m, n4);
    merge_b_kernel<<<(FDIM + 255) / 256, 256, 0, stream>>>(bb1, tb1, lam, b1m, FDIM);
    merge_b_kernel<<<(HDIM + 255) / 256, 256, 0, stream>>>(bb2, tb2, lam, b2m, HDIM);
  }

  // 6) h = relu(X @ w1m^T + b1m)   (M=8192, N=4096, K=1024), bf16 out
  gemm8p<1, 256><<<dim3(FDIM / 256, SB / 256), 512, 131072, stream>>>(
      Xbf, w1m, b1m, hbuf, SB, FDIM, HDIM);

  // 7) out = h @ w2m^T + b2m       (M=8192, N=1024, K=4096), fp32 out
  gemm8p<2, 128><<<dim3(HDIM / 128, SB / 256), 512, 98304, stream>>>(
      hbuf, w2m, b2m, out, SB, HDIM, FDIM);
}